// Round 7
// baseline (1591.447 us; speedup 1.0000x reference)
//
#include <hip/hip_runtime.h>

#define BATCH 64
#define SEQ   4096
#define ISZ   64
#define RSZ   128
constexpr float LEAK = 0.5f;

typedef float f32x4_t __attribute__((ext_vector_type(4)));
typedef float f32x2_t __attribute__((ext_vector_type(2)));

__device__ __forceinline__ float fast_tanh(float x) {
    float e = __expf(2.0f * x);
    return 1.0f - 2.0f / (e + 1.0f);
}

// x + cross-lane(x) via DPP — pure VALU, no DS ops.
// 0xB1 = quad_perm[1,0,3,2] (xor1), 0x4E = quad_perm[2,3,0,1] (xor2),
// 0x141 = row_half_mirror (lane l <-> l^7 within each 8-lane half-row).
template <int CTRL>
__device__ __forceinline__ float dpp_add(float x) {
    int y = __builtin_amdgcn_update_dpp(0, __builtin_bit_cast(int, x),
                                        CTRL, 0xF, 0xF, true);
    return x + __builtin_bit_cast(float, y);
}

// ---------------------------------------------------------------------------
// Kernel 1: projection. out[row][r] = tanh(sum_j x[row][j] * w_in[r][j])
// ---------------------------------------------------------------------------
__global__ __launch_bounds__(256) void proj_kernel(
        const float* __restrict__ x, const float* __restrict__ w_in,
        float* __restrict__ out) {
    __shared__ float wT[ISZ][RSZ];
    __shared__ float xs[32][ISZ];

    const int tid = threadIdx.x;

    for (int idx = tid; idx < RSZ * ISZ / 4; idx += 256) {
        const int r  = idx >> 4;
        const int j4 = (idx & 15) << 2;
        const float4 v = reinterpret_cast<const float4*>(w_in)[idx];
        wT[j4 + 0][r] = v.x; wT[j4 + 1][r] = v.y;
        wT[j4 + 2][r] = v.z; wT[j4 + 3][r] = v.w;
    }
    const long row0 = (long)blockIdx.x * 32;
    #pragma unroll
    for (int q = 0; q < 2; ++q) {
        const int idx = tid + q * 256;
        reinterpret_cast<float4*>(&xs[0][0])[idx] =
            reinterpret_cast<const float4*>(x + row0 * ISZ)[idx];
    }
    __syncthreads();

    const int rq = tid & 31;
    const int rp = tid >> 5;
    const int r0 = rq << 2;
    const int ra = rp << 2;

    float acc[4][4] = {};
    #pragma unroll
    for (int j4 = 0; j4 < ISZ; j4 += 4) {
        float4 xv[4];
        #pragma unroll
        for (int m = 0; m < 4; ++m)
            xv[m] = *reinterpret_cast<const float4*>(&xs[ra + m][j4]);
        #pragma unroll
        for (int k = 0; k < 4; ++k) {
            const float4 w = *reinterpret_cast<const float4*>(&wT[j4 + k][r0]);
            #pragma unroll
            for (int m = 0; m < 4; ++m) {
                const float xm = k == 0 ? xv[m].x : k == 1 ? xv[m].y
                               : k == 2 ? xv[m].z : xv[m].w;
                acc[m][0] += xm * w.x; acc[m][1] += xm * w.y;
                acc[m][2] += xm * w.z; acc[m][3] += xm * w.w;
            }
        }
    }
    #pragma unroll
    for (int m = 0; m < 4; ++m) {
        float4 o;
        o.x = fast_tanh(acc[m][0]); o.y = fast_tanh(acc[m][1]);
        o.z = fast_tanh(acc[m][2]); o.w = fast_tanh(acc[m][3]);
        *reinterpret_cast<float4*>(&out[(row0 + ra + m) * RSZ + r0]) = o;
    }
}

// ---------------------------------------------------------------------------
// Kernel 2: sequential scan. One block per batch, 256 threads = 4 waves.
// Wave w owns outputs [32w,32w+32); lane = (grp = lane>>3, sl = lane&7):
// partial dots for rows r0..r0+3 (r0 = 32w+4grp) over k-slice [16sl,16sl+16)
// via 16 v_pk_fma_f32 (f32x2 elementwise fma). Reduce: xor1+xor2 DPP (quad-
// uniform half-sums), then each lane SELECTS acc idx = sl<4 ? sl : 7-sl
// (idx(l)==idx(l^7)), one row_half_mirror DPP completes the full sum of the
// lane's owned output r0+idx. ONE ACT per lane (was 4 — 8x redundant trans
// ops gone). Lanes sl<4 write h-LDS (b32), sl>=4 write the stage ring (b32).
// Stage ring + 8-step NT flush and 4-deep scalar u prefetch as round 6.
// Raw s_barrier + lgkmcnt(0)-only wait (global stores never drained).
// ---------------------------------------------------------------------------
__global__ __launch_bounds__(256) void scan_kernel(
        const float* __restrict__ w_res, float* __restrict__ io) {
    __shared__ float h[2][160];          // element k -> word 20*(k>>4)+(k&15)
    __shared__ float stage[16 * 128];    // 8 KB ring, slot = t & 15

    const int tid  = threadIdx.x;
    const int lane = tid & 63;
    const int wave = tid >> 6;
    const int grp  = lane >> 3;          // 8 output groups of 4
    const int sl   = lane & 7;           // 8 k-slices of 16
    const int r0   = wave * 32 + grp * 4;
    const int kb   = sl * 16;
    const int idx  = (sl < 4) ? sl : (7 - sl);   // owned output within group
    const int rown = r0 + idx;                   // owned output element

    // W_res rows r0..r0+3, cols kb..kb+15 -> 64 VGPRs as f32x2 pairs
    f32x2_t w2[4][8];
    #pragma unroll
    for (int rr = 0; rr < 4; ++rr) {
        #pragma unroll
        for (int kk = 0; kk < 16; kk += 4) {
            const f32x4_t v = *reinterpret_cast<const f32x4_t*>(
                &w_res[(r0 + rr) * RSZ + kb + kk]);
            w2[rr][kk / 2 + 0] = v.xy;
            w2[rr][kk / 2 + 1] = v.zw;
        }
    }

    for (int i = tid; i < 2 * 160; i += 256) (&h[0][0])[i] = 0.0f;

    float* const out  = io + (long)blockIdx.x * (SEQ * RSZ);
    const float* uptr = out + rown;
    const int  rbase  = 20 * sl;                          // h read word base
    const int  hw     = 20 * (rown >> 4) + (rown & 15);   // h write word
    const bool selb0  = idx & 1;
    const bool selb1  = idx & 2;

    // 4-deep scalar u prefetch ring (static indices)
    float u[4];
    #pragma unroll
    for (int s = 0; s < 4; ++s) u[s] = uptr[s * RSZ];
    float hreg = 0.f;
    __syncthreads();

    // nh = 0.5*h + 0.5*tanh(v) = fma(0.5,h,0.5) - 1/(exp2(2*log2e*v)+1)
    #define ACT(HH, VV)                                                       \
        (fmaf(0.5f, (HH), 0.5f) -                                             \
         __builtin_amdgcn_rcpf(                                               \
             __builtin_amdgcn_exp2f((VV) * 2.885390082f) + 1.0f))

    #define STEP(S)                                                           \
    {                                                                         \
        const float uc = u[(S) & 3];                                          \
        if (t0 + (S) + 4 < SEQ)                                               \
            u[(S) & 3] = uptr[(t0 + (S) + 4) * RSZ];                          \
        f32x2_t acc0 = {0.f, 0.f}, acc1 = {0.f, 0.f};                         \
        f32x2_t acc2 = {0.f, 0.f}, acc3 = {0.f, 0.f};                         \
        _Pragma("unroll")                                                     \
        for (int q = 0; q < 4; ++q) {                                         \
            const f32x4_t hv = *reinterpret_cast<const f32x4_t*>(             \
                &h[(S) & 1][rbase + q * 4]);                                  \
            const f32x2_t lo = hv.xy, hi = hv.zw;                             \
            acc0 = __builtin_elementwise_fma(lo, w2[0][2*q+0], acc0);         \
            acc0 = __builtin_elementwise_fma(hi, w2[0][2*q+1], acc0);         \
            acc1 = __builtin_elementwise_fma(lo, w2[1][2*q+0], acc1);         \
            acc1 = __builtin_elementwise_fma(hi, w2[1][2*q+1], acc1);         \
            acc2 = __builtin_elementwise_fma(lo, w2[2][2*q+0], acc2);         \
            acc2 = __builtin_elementwise_fma(hi, w2[2][2*q+1], acc2);         \
            acc3 = __builtin_elementwise_fma(lo, w2[3][2*q+0], acc3);         \
            acc3 = __builtin_elementwise_fma(hi, w2[3][2*q+1], acc3);         \
        }                                                                     \
        float a0 = acc0.x + acc0.y, a1 = acc1.x + acc1.y;                     \
        float a2 = acc2.x + acc2.y, a3 = acc3.x + acc3.y;                     \
        a0 = dpp_add<0xB1>(a0); a1 = dpp_add<0xB1>(a1);                       \
        a2 = dpp_add<0xB1>(a2); a3 = dpp_add<0xB1>(a3);                       \
        a0 = dpp_add<0x4E>(a0); a1 = dpp_add<0x4E>(a1);                       \
        a2 = dpp_add<0x4E>(a2); a3 = dpp_add<0x4E>(a3);                       \
        const float s01  = selb0 ? a1 : a0;                                   \
        const float s23  = selb0 ? a3 : a2;                                   \
        float asel = selb1 ? s23 : s01;                                       \
        asel = dpp_add<0x141>(asel);      /* partner l^7 holds same idx */    \
        const float nh = ACT(hreg, uc + asel);                                \
        hreg = nh;                                                            \
        if (sl < 4)                                                           \
            h[1 - ((S) & 1)][hw] = nh;                                        \
        else                                                                  \
            stage[((t0 & 8) + (S)) * 128 + rown] = nh;                        \
        asm volatile("s_waitcnt lgkmcnt(0)" ::: "memory");                    \
        __builtin_amdgcn_s_barrier();                                         \
        asm volatile("" ::: "memory");                                        \
    }

    const int fstep = tid >> 5;          // 0..7: which step of the half
    const int felem = (tid & 31) * 4;    // 0..124: element quad

    for (int t0 = 0; t0 < SEQ; t0 += 8) {
        STEP(0) STEP(1) STEP(2) STEP(3)
        STEP(4) STEP(5) STEP(6) STEP(7)
        // Flush this iteration's 8 staged steps: coalesced LDS read + NT store
        const f32x4_t v = *reinterpret_cast<const f32x4_t*>(
            &stage[((t0 & 8) + fstep) * 128 + felem]);
        __builtin_nontemporal_store(v,
            reinterpret_cast<f32x4_t*>(&out[(t0 + fstep) * RSZ + felem]));
    }
    #undef STEP
    #undef ACT
}

extern "C" void kernel_launch(void* const* d_in, const int* in_sizes, int n_in,
                              void* d_out, int out_size, void* d_ws, size_t ws_size,
                              hipStream_t stream) {
    const float* x     = (const float*)d_in[0];
    const float* w_in  = (const float*)d_in[1];
    const float* w_res = (const float*)d_in[2];
    float* out = (float*)d_out;

    proj_kernel<<<(BATCH * SEQ) / 32, 256, 0, stream>>>(x, w_in, out);
    scan_kernel<<<BATCH, 256, 0, stream>>>(w_res, out);
}